// Round 8
// baseline (109.718 us; speedup 1.0000x reference)
//
#include <hip/hip_runtime.h>

#define WINDOW   512
#define STEPSZ   256
#define NFRAMES  127
#define NSAMP    32768
#define NBATCH   512
#define NFREQ    256
#define BM       64
#define SAMP_TILE 16640          // 65 * 256 samples per tile
#define NPS      65

typedef __attribute__((ext_vector_type(8))) short short8;   // 8 x bf16
typedef __attribute__((ext_vector_type(4))) float f32x4;
typedef __attribute__((ext_vector_type(4))) float f4;

// Verified pattern (G4): spread row-bits into the 16B-slot bits.
#define SWZ(byt) ((byt) ^ ((((byt) >> 9) & 7) << 4))

static __device__ __forceinline__ short f2bf(float x) {
    union { float f; unsigned u; } v; v.f = x;
    unsigned r = (v.u + 0x7fffu + ((v.u >> 16) & 1u)) >> 16;
    return (short)r;
}

// ---- kernel 1: normalize basis -> bf16 fragment-major layout in d_ws ----
// frag[(ntg*16 + kk)*64 + (kgrp*16 + rlane)][8] holds
// B[n = ntg*16 + rlane][k = kk*32 + kgrp*8 + j]; real ntg 0..15, imag 16..31.
__global__ __launch_bounds__(256) void prep_kernel(const float* __restrict__ br,
                                                   const float* __restrict__ bi,
                                                   short* __restrict__ Bf) {
    const int lane = threadIdx.x & 63;
    const int wid  = threadIdx.x >> 6;
    const int k    = blockIdx.x * 4 + wid;          // freq 0..255
    const float* pr = br + (size_t)k * WINDOW + lane * 8;
    const float* pi = bi + (size_t)k * WINDOW + lane * 8;
    f4 r0 = *(const f4*)pr;
    f4 r1 = *(const f4*)(pr + 4);
    f4 i0 = *(const f4*)pi;
    f4 i1 = *(const f4*)(pi + 4);
    float ss = 0.f;
#pragma unroll
    for (int j = 0; j < 4; ++j)
        ss += r0[j]*r0[j] + r1[j]*r1[j] + i0[j]*i0[j] + i1[j]*i1[j];
#pragma unroll
    for (int d = 1; d < 64; d <<= 1) ss += __shfl_xor(ss, d, 64);
    const float inv = 1.0f / (sqrtf(ss) + 1e-8f);
    short8 hr, hi;
#pragma unroll
    for (int j = 0; j < 4; ++j) {
        hr[j]     = f2bf(r0[j] * inv);
        hr[j + 4] = f2bf(r1[j] * inv);
        hi[j]     = f2bf(i0[j] * inv);
        hi[j + 4] = f2bf(i1[j] * inv);
    }
    const int kk = lane >> 2, kgrp = lane & 3;
    const int rl  = k & 15;
    const int ntR = k >> 4;
    const int ntI = 16 + (k >> 4);
    *(short8*)(Bf + ((size_t)(ntR * 16 + kk) * 64 + kgrp * 16 + rl) * 8) = hr;
    *(short8*)(Bf + ((size_t)(ntI * 16 + kk) * 64 + kgrp * 16 + rl) * 8) = hi;
}

#define MFMA16(AB)                                                                  \
    acc[0][0] = __builtin_amdgcn_mfma_f32_16x16x32_bf16(a0, AB##0, acc[0][0], 0, 0, 0); \
    acc[1][0] = __builtin_amdgcn_mfma_f32_16x16x32_bf16(a1, AB##0, acc[1][0], 0, 0, 0); \
    acc[2][0] = __builtin_amdgcn_mfma_f32_16x16x32_bf16(a2, AB##0, acc[2][0], 0, 0, 0); \
    acc[3][0] = __builtin_amdgcn_mfma_f32_16x16x32_bf16(a3, AB##0, acc[3][0], 0, 0, 0); \
    acc[0][1] = __builtin_amdgcn_mfma_f32_16x16x32_bf16(a0, AB##1, acc[0][1], 0, 0, 0); \
    acc[1][1] = __builtin_amdgcn_mfma_f32_16x16x32_bf16(a1, AB##1, acc[1][1], 0, 0, 0); \
    acc[2][1] = __builtin_amdgcn_mfma_f32_16x16x32_bf16(a2, AB##1, acc[2][1], 0, 0, 0); \
    acc[3][1] = __builtin_amdgcn_mfma_f32_16x16x32_bf16(a3, AB##1, acc[3][1], 0, 0, 0); \
    acc[0][2] = __builtin_amdgcn_mfma_f32_16x16x32_bf16(a0, AB##2, acc[0][2], 0, 0, 0); \
    acc[1][2] = __builtin_amdgcn_mfma_f32_16x16x32_bf16(a1, AB##2, acc[1][2], 0, 0, 0); \
    acc[2][2] = __builtin_amdgcn_mfma_f32_16x16x32_bf16(a2, AB##2, acc[2][2], 0, 0, 0); \
    acc[3][2] = __builtin_amdgcn_mfma_f32_16x16x32_bf16(a3, AB##2, acc[3][2], 0, 0, 0); \
    acc[0][3] = __builtin_amdgcn_mfma_f32_16x16x32_bf16(a0, AB##3, acc[0][3], 0, 0, 0); \
    acc[1][3] = __builtin_amdgcn_mfma_f32_16x16x32_bf16(a1, AB##3, acc[1][3], 0, 0, 0); \
    acc[2][3] = __builtin_amdgcn_mfma_f32_16x16x32_bf16(a2, AB##3, acc[2][3], 0, 0, 0); \
    acc[3][3] = __builtin_amdgcn_mfma_f32_16x16x32_bf16(a3, AB##3, acc[3][3], 0, 0, 0);

// ---- kernel 2: fused norms + bf16 MFMA GEMM --------------------------------
// grid = 512 b * 2 m-halves = 1024 blocks; 512 thr (8 waves).
// Block = 64 frames x 512 cols; wave = 4m x 4n (acc 64 AGPR). 2 blocks/CU
// resident -> phases of the two blocks overlap (staging hides store bursts).
__global__ __launch_bounds__(512, 4) void mel_kernel(const float* __restrict__ audio,
                                                     const short* __restrict__ Bf,
                                                     float* __restrict__ out) {
    __shared__ short smp[SAMP_TILE];   // 33280 B, swizzled bf16 samples
    __shared__ float ps[NPS];
    __shared__ float invn[BM];

    const int tid  = threadIdx.x;
    const int lane = tid & 63;
    const int wid  = tid >> 6;          // 0..7

    const int b   = blockIdx.x >> 1;
    const int mh  = blockIdx.x & 1;
    const int f0  = mh * BM;

    float* out_norms = out;
    float* out_real  = out + 65024;
    float* out_imag  = out + 65024 + 16646144;

    const float* abase = audio + (size_t)b * NSAMP + f0 * STEPSZ;
    const int smax = NSAMP - f0 * STEPSZ - 8;

    const int rlane = lane & 15;
    const int kgrp  = lane >> 4;
    const int ntg0  = wid * 4;          // 4 n-tiles per wave

    const short* bp0 = Bf + ((size_t)(ntg0 + 0) * 16 * 64 + lane) * 8;
    const short* bp1 = Bf + ((size_t)(ntg0 + 1) * 16 * 64 + lane) * 8;
    const short* bp2 = Bf + ((size_t)(ntg0 + 2) * 16 * 64 + lane) * 8;
    const short* bp3 = Bf + ((size_t)(ntg0 + 3) * 16 * 64 + lane) * 8;

    // depth-2 prefetch: even buffer (kk) and odd buffer (kk+1)
    short8 e0 = *(const short8*)bp0, e1 = *(const short8*)bp1,
           e2 = *(const short8*)bp2, e3 = *(const short8*)bp3;
    short8 o0 = *(const short8*)(bp0 + 512), o1 = *(const short8*)(bp1 + 512),
           o2 = *(const short8*)(bp2 + 512), o3 = *(const short8*)(bp3 + 512);

    // ---- Phase 1: stream 8 samples/thread; fused norm partials ----
#pragma unroll
    for (int it = 0; it < 5; ++it) {
        const int sl = it * 4096 + tid * 8;
        float ss = 0.f;
        if (sl < SAMP_TILE) {
            const int slc = sl < smax ? sl : smax;
            f4 v0 = *(const f4*)(abase + slc);
            f4 v1 = *(const f4*)(abase + slc + 4);
            short8 h;
#pragma unroll
            for (int q = 0; q < 4; ++q) {
                ss += v0[q]*v0[q] + v1[q]*v1[q];
                h[q]     = f2bf(v0[q]);
                h[q + 4] = f2bf(v1[q]);
            }
            const int byt = sl * 2;
            *(short8*)((char*)smp + SWZ(byt)) = h;
        }
        ss += __shfl_xor(ss, 1, 64);
        ss += __shfl_xor(ss, 2, 64);
        ss += __shfl_xor(ss, 4, 64);
        ss += __shfl_xor(ss, 8, 64);
        ss += __shfl_xor(ss, 16, 64);
        const int chunk = (it * 4096 + tid * 8) >> 8;
        if ((tid & 31) == 0 && chunk < NPS) ps[chunk] = ss;
    }
    __syncthreads();

    if (tid < BM) {
        const float nrm = sqrtf(ps[tid] + ps[tid + 1]);
        const int fr = f0 + tid;
        if (fr < NFRAMES) out_norms[b * NFRAMES + fr] = nrm;
        invn[tid] = 1.0f / (nrm + 1e-8f);
    }

    // ---- Phase 2: K-loop ----
    const int rb = rlane * 512 + kgrp * 16;
    const int X0 = (rlane & 7) << 4;
    const int X1 = ((rlane + 1) & 7) << 4;
    const char* sb = (const char*)smp;

    f32x4 acc[4][4];
#pragma unroll
    for (int mt = 0; mt < 4; ++mt)
#pragma unroll
        for (int nt = 0; nt < 4; ++nt) acc[mt][nt] = (f32x4)0.f;

#pragma unroll
    for (int kk = 0; kk < 16; ++kk) {
        const int X  = (kk < 8) ? X0 : X1;
        const int kb = kk * 64;
        short8 a0 = *(const short8*)(sb + ((rb + 0 * 8192 + kb) ^ X));
        short8 a1 = *(const short8*)(sb + ((rb + 1 * 8192 + kb) ^ X));
        short8 a2 = *(const short8*)(sb + ((rb + 2 * 8192 + kb) ^ X));
        short8 a3 = *(const short8*)(sb + ((rb + 3 * 8192 + kb) ^ X));
        if ((kk & 1) == 0) {
            MFMA16(e)
            if (kk < 14) {
                e0 = *(const short8*)(bp0 + (size_t)(kk + 2) * 512);
                e1 = *(const short8*)(bp1 + (size_t)(kk + 2) * 512);
                e2 = *(const short8*)(bp2 + (size_t)(kk + 2) * 512);
                e3 = *(const short8*)(bp3 + (size_t)(kk + 2) * 512);
            }
        } else {
            MFMA16(o)
            if (kk < 14) {
                o0 = *(const short8*)(bp0 + (size_t)(kk + 2) * 512);
                o1 = *(const short8*)(bp1 + (size_t)(kk + 2) * 512);
                o2 = *(const short8*)(bp2 + (size_t)(kk + 2) * 512);
                o3 = *(const short8*)(bp3 + (size_t)(kk + 2) * 512);
            }
        }
    }
    __syncthreads();   // invn visible to all epilogue readers

    // ---- Epilogue: scale by 1/norm, store ----
#pragma unroll
    for (int mt = 0; mt < 4; ++mt) {
        const int rbase = mt * 16 + kgrp * 4;
#pragma unroll
        for (int nt = 0; nt < 4; ++nt) {
            const int n = (ntg0 + nt) * 16 + rlane;
            float* dst = (n < NFREQ) ? out_real : out_imag;
            const int kcol = n & (NFREQ - 1);
#pragma unroll
            for (int j = 0; j < 4; ++j) {
                const int r  = rbase + j;
                const int fr = f0 + r;
                if (fr < NFRAMES)
                    dst[((size_t)b * NFRAMES + fr) * NFREQ + kcol] = acc[mt][nt][j] * invn[r];
            }
        }
    }
}

extern "C" void kernel_launch(void* const* d_in, const int* in_sizes, int n_in,
                              void* d_out, int out_size, void* d_ws, size_t ws_size,
                              hipStream_t stream) {
    const float* audio = (const float*)d_in[0];
    const float* br    = (const float*)d_in[1];
    const float* bi    = (const float*)d_in[2];
    float* out = (float*)d_out;
    short* Bf  = (short*)d_ws;               // 512x512 bf16 = 512 KiB

    prep_kernel<<<64, 256, 0, stream>>>(br, bi, Bf);
    mel_kernel<<<NBATCH * 2, 512, 0, stream>>>(audio, Bf, out);
}